// Round 14
// baseline (410.996 us; speedup 1.0000x reference)
//
#include <hip/hip_runtime.h>
#include <cfloat>

#define N_NODES 50000
#define N_EDGES 1600000
#define DX      128
#define DH      64
#define KH      4
#define NC      256                   // KH*DH
#define NEG_SLOPE 0.01f
#define SCAN_BLOCKS 196               // bucket count (dst>>8)
#define BIN_BLOCKS 250
#define BIN_CHUNK  6400               // 250*6400 = 1.6M edges exactly

__device__ __forceinline__ unsigned pack_bf16(float a, float b) {
    unsigned ua = __float_as_uint(a), ub = __float_as_uint(b);
    ua = (ua + 0x7FFFu + ((ua >> 16) & 1u)) >> 16;          // RNE
    ub = (ub + 0x7FFFu + ((ub >> 16) & 1u)) & 0xFFFF0000u;
    return ua | ub;
}

// ---------- bucket histogram (per-block partials, no atomics/init) + fused setup ----------
__global__ void __launch_bounds__(256) k_bhist(const int* __restrict__ ei,
                                               int* __restrict__ bcnt_part,
                                               const float* __restrict__ Ww,
                                               float* __restrict__ Wt,
                                               float* __restrict__ colsum) {
    __shared__ int bh[SCAN_BLOCKS];
    int t = threadIdx.x;
    if (t < SCAN_BLOCKS) bh[t] = 0;
    __syncthreads();
    int e0 = blockIdx.x * BIN_CHUNK;
#pragma unroll 5
    for (int k = 0; k < BIN_CHUNK / 256; ++k) {
        int dst = ei[N_EDGES + e0 + t + k * 256];
        atomicAdd(&bh[dst >> 8], 1);
    }
    // fused setup work (independent of histogram)
    int i = blockIdx.x * 256 + t;     // 0..63999
    if (i < NC) colsum[i] = 0.f;
    if (i < DX * NC) {
        int d = i >> 8, c = i & 255;
        Wt[d * NC + c] = Ww[c * DX + d];
    }
    __syncthreads();
    if (t < SCAN_BLOCKS) bcnt_part[blockIdx.x * SCAN_BLOCKS + t] = bh[t];
}

// ---------- Wx GEMM + fused si/sj epilogue; writes bf16 copy for the gather ----------
__global__ void __launch_bounds__(256) k_gemm1(const float* __restrict__ x,
                                               const float* __restrict__ Wt,
                                               const float* __restrict__ Wb,
                                               const float* __restrict__ aw,
                                               const float* __restrict__ ab,
                                               uint2* __restrict__ Wxb,
                                               float* __restrict__ sic,
                                               float* __restrict__ sjc) {
    int wave = blockIdx.x * 4 + __builtin_amdgcn_readfirstlane(threadIdx.x >> 6);
    if (wave >= N_NODES / 8) return;           // 50000 % 8 == 0
    int lane = threadIdx.x & 63;
    int kh = lane >> 4, lq = lane & 15;
    int n0 = wave * 8;
    const float4* WtV = (const float4*)Wt;
    float acc[8][4];
#pragma unroll
    for (int r = 0; r < 8; ++r)
#pragma unroll
        for (int q = 0; q < 4; ++q) acc[r][q] = 0.f;

    for (int d = 0; d < DX; d += 4) {
        float xr[8][4];
#pragma unroll
        for (int r = 0; r < 8; ++r) {
            float4 v = *(const float4*)&x[(size_t)(n0 + r) * DX + d];
            xr[r][0] = v.x; xr[r][1] = v.y; xr[r][2] = v.z; xr[r][3] = v.w;
        }
#pragma unroll
        for (int q = 0; q < 4; ++q) {
            float4 wv = WtV[(size_t)(d + q) * 64 + lane];
#pragma unroll
            for (int r = 0; r < 8; ++r) {
                acc[r][0] += xr[r][q] * wv.x;
                acc[r][1] += xr[r][q] * wv.y;
                acc[r][2] += xr[r][q] * wv.z;
                acc[r][3] += xr[r][q] * wv.w;
            }
        }
    }
    float4 bias = ((const float4*)Wb)[lane];
    const float* awi = aw + kh * 2 * DH + lq * 4;
    const float* awj = awi + DH;
    float ai0 = awi[0], ai1 = awi[1], ai2 = awi[2], ai3 = awi[3];
    float aj0 = awj[0], aj1 = awj[1], aj2 = awj[2], aj3 = awj[3];
    float abk = ab[kh];
#pragma unroll
    for (int r = 0; r < 8; ++r) {
        float o0 = acc[r][0] + bias.x, o1 = acc[r][1] + bias.y;
        float o2 = acc[r][2] + bias.z, o3 = acc[r][3] + bias.w;
        uint2 pk; pk.x = pack_bf16(o0, o1); pk.y = pack_bf16(o2, o3);
        Wxb[(size_t)(n0 + r) * 64 + lane] = pk;
        float pi = o0 * ai0 + o1 * ai1 + o2 * ai2 + o3 * ai3;
        float pj = o0 * aj0 + o1 * aj1 + o2 * aj2 + o3 * aj3;
#pragma unroll
        for (int off = 8; off >= 1; off >>= 1) {
            pi += __shfl_xor(pi, off, 64);
            pj += __shfl_xor(pj, off, 64);
        }
        if (lq == 0) {
            sic[(n0 + r) * 4 + kh] = pi + abk;   // fold ab into dst-side score
            sjc[(n0 + r) * 4 + kh] = pj;
        }
    }
}

// ---------- scan 196 bucket counts (sum 250 partials) -> bbase + bcur ----------
__global__ void __launch_bounds__(256) k_scanb(const int* __restrict__ bcnt_part,
                                               int* __restrict__ bbase,
                                               int* __restrict__ bcur) {
    __shared__ int s[256];
    int t = threadIdx.x;
    int v = 0;
    if (t < SCAN_BLOCKS) {
#pragma unroll 5
        for (int b = 0; b < BIN_BLOCKS; ++b) v += bcnt_part[b * SCAN_BLOCKS + t];
    }
    s[t] = v;
    __syncthreads();
#pragma unroll
    for (int off = 1; off < 256; off <<= 1) {
        int u = (t >= off) ? s[t - off] : 0;
        __syncthreads();
        s[t] += u;
        __syncthreads();
    }
    if (t < SCAN_BLOCKS) {
        int ex = s[t] - v;
        bbase[t] = ex;
        bcur[t] = ex;
    }
    if (t == SCAN_BLOCKS - 1) bbase[SCAN_BLOCKS] = s[t];   // = N_EDGES
}

// ---------- binning pass: edges -> 196 dst-buckets, dense chunked writes ----------
__global__ void __launch_bounds__(256) k_bin(const int* __restrict__ ei,
                                             int* __restrict__ bcur,
                                             unsigned* __restrict__ binned) {
    __shared__ int bh[SCAN_BLOCKS];   // count, then local cursor
    __shared__ int bb[SCAN_BLOCKS];   // reserved global base
    int t = threadIdx.x;
    if (t < SCAN_BLOCKS) bh[t] = 0;
    __syncthreads();
    int e0 = blockIdx.x * BIN_CHUNK;
#pragma unroll 5
    for (int k = 0; k < BIN_CHUNK / 256; ++k) {
        int dst = ei[N_EDGES + e0 + t + k * 256];
        atomicAdd(&bh[dst >> 8], 1);
    }
    __syncthreads();
    if (t < SCAN_BLOCKS) {
        bb[t] = atomicAdd(&bcur[t], bh[t]);
        bh[t] = 0;
    }
    __syncthreads();
#pragma unroll 5
    for (int k = 0; k < BIN_CHUNK / 256; ++k) {
        int e = e0 + t + k * 256;
        int src = ei[e];
        int dst = ei[N_EDGES + e];
        int b = dst >> 8;
        int lo = atomicAdd(&bh[b], 1);
        binned[bb[b] + lo] = (unsigned)src | ((unsigned)(dst & 255) << 16);   // src < 2^16
    }
}

// ---------- fused per-bucket: count dsts + scan + rowstart + self-loop + scatter ----------
__global__ void __launch_bounds__(256) k_scatter3(const unsigned* __restrict__ binned,
                                                  const int* __restrict__ bbase,
                                                  int* __restrict__ rowstart,
                                                  int* __restrict__ csr_src) {
    __shared__ int lcnt[256];
    __shared__ int lcur[256];
    __shared__ int s[256];
    int t = threadIdx.x, b = blockIdx.x;
    int e0 = bbase[b], e1 = bbase[b + 1];
    lcnt[t] = 0;
    __syncthreads();
    for (int i = e0 + t; i < e1; i += 256)
        atomicAdd(&lcnt[binned[i] >> 16], 1);
    __syncthreads();
    int v = lcnt[t];
    s[t] = v;
    __syncthreads();
#pragma unroll
    for (int off = 1; off < 256; off <<= 1) {
        int u = (t >= off) ? s[t - off] : 0;
        __syncthreads();
        s[t] += u;
        __syncthreads();
    }
    int d = b * 256 + t;
    int base_b = e0 + 256 * b;              // edges before bucket + self-loops before bucket
    if (d < N_NODES) {
        int rs = base_b + (s[t] - v) + t;   // + t self-loops within bucket
        rowstart[d] = rs;
        csr_src[rs] = d;                    // self-loop edge placed first
        lcur[t] = rs + 1;
    } else lcur[t] = 0;
    if (b == 0 && t == 0) rowstart[N_NODES] = N_EDGES + N_NODES;
    __syncthreads();
    for (int i = e0 + t; i < e1; i += 256) {
        unsigned u = binned[i];
        int pos = atomicAdd(&lcur[u >> 16], 1);
        csr_src[pos] = (int)(u & 0xFFFFu);
    }
}

// ---------- aggregation: HALF-WAVE per dst (2 edges/wave-iter), uint4 gather ----------
// lane owns 8 cols (16B); 32 lanes x 16B = same 512B coalesced row, half the
// per-edge VALU. den is computed redundantly by the 8 lanes of each head group.
__global__ void __launch_bounds__(256) k_aggregate(const int* __restrict__ rowstart,
                                                   const int* __restrict__ csr_src,
                                                   const float* __restrict__ sic,
                                                   const float* __restrict__ sjc,
                                                   const uint4* __restrict__ Wxb,
                                                   uint4* __restrict__ expb) {
    int tid = threadIdx.x;
    int dst = blockIdx.x * 8 + (tid >> 5);   // grid = 6250, exact
    int lq = tid & 31;
    int kh = lq >> 3;
    int i0 = rowstart[dst], iend = rowstart[dst + 1];
    float sval = sic[dst * 4 + kh];

    float den = 0.f;
    float a0 = 0.f, a1 = 0.f, a2 = 0.f, a3 = 0.f;
    float a4 = 0.f, a5 = 0.f, a6 = 0.f, a7 = 0.f;
    int i = i0;
    for (; i + 8 <= iend; i += 8) {          // per-half bounds; exec mask handles tails
        int ss[8]; uint4 gg[8]; float tt[8];
#pragma unroll
        for (int u = 0; u < 8; ++u) ss[u] = csr_src[i + u];
#pragma unroll
        for (int u = 0; u < 8; ++u) gg[u] = Wxb[(size_t)ss[u] * 32 + lq];
#pragma unroll
        for (int u = 0; u < 8; ++u) tt[u] = sjc[ss[u] * 4 + kh];
#pragma unroll
        for (int u = 0; u < 8; ++u) {
            float e = sval + tt[u];
            e = (e >= 0.f) ? e : NEG_SLOPE * e;
            float ex = __expf(e);
            den += ex;
            a0 += ex * __uint_as_float(gg[u].x << 16);
            a1 += ex * __uint_as_float(gg[u].x & 0xFFFF0000u);
            a2 += ex * __uint_as_float(gg[u].y << 16);
            a3 += ex * __uint_as_float(gg[u].y & 0xFFFF0000u);
            a4 += ex * __uint_as_float(gg[u].z << 16);
            a5 += ex * __uint_as_float(gg[u].z & 0xFFFF0000u);
            a6 += ex * __uint_as_float(gg[u].w << 16);
            a7 += ex * __uint_as_float(gg[u].w & 0xFFFF0000u);
        }
    }
    for (; i < iend; ++i) {
        int s = csr_src[i];
        uint4 g = Wxb[(size_t)s * 32 + lq];
        float e = sval + sjc[s * 4 + kh];
        e = (e >= 0.f) ? e : NEG_SLOPE * e;
        float ex = __expf(e);
        den += ex;
        a0 += ex * __uint_as_float(g.x << 16);
        a1 += ex * __uint_as_float(g.x & 0xFFFF0000u);
        a2 += ex * __uint_as_float(g.y << 16);
        a3 += ex * __uint_as_float(g.y & 0xFFFF0000u);
        a4 += ex * __uint_as_float(g.z << 16);
        a5 += ex * __uint_as_float(g.z & 0xFFFF0000u);
        a6 += ex * __uint_as_float(g.w << 16);
        a7 += ex * __uint_as_float(g.w & 0xFFFF0000u);
    }
    float r = 1.f / den;
    uint4 pk;
    pk.x = pack_bf16(__expf(a0 * r), __expf(a1 * r));
    pk.y = pack_bf16(__expf(a2 * r), __expf(a3 * r));
    pk.z = pack_bf16(__expf(a4 * r), __expf(a5 * r));
    pk.w = pack_bf16(__expf(a6 * r), __expf(a7 * r));
    expb[(size_t)dst * 32 + lq] = pk;        // bf16 exp(agg), cols 8lq..8lq+7
}

// ---------- column sums of exp(agg), bf16 input, 2 cols/thread ----------
__global__ void __launch_bounds__(256) k_colsum(const unsigned* __restrict__ expb,
                                                float* __restrict__ colsum) {
    int tid = threadIdx.x;
    int cp = tid & 127;            // uint index within row (cols 2cp, 2cp+1)
    int ro = tid >> 7;             // row parity
    int base = blockIdx.x * 196;
    int r1 = min(base + 196, N_NODES);
    float s0 = 0.f, s1 = 0.f;
    for (int r = base + ro; r < r1; r += 2) {
        unsigned u = expb[(size_t)r * 128 + cp];
        s0 += __uint_as_float(u << 16);
        s1 += __uint_as_float(u & 0xFFFF0000u);
    }
    atomicAdd(&colsum[2 * cp], s0);
    atomicAdd(&colsum[2 * cp + 1], s1);
}

// ---------- Ws[c][j] = Wo_w[j][c] / colsum[c] ----------
__global__ void k_prepWs(const float* __restrict__ Wo_w, const float* __restrict__ colsum,
                         float* __restrict__ Ws) {
    int i = blockIdx.x * 256 + threadIdx.x;   // 16384 total
    int c = i >> 6, j = i & 63;
    Ws[c * 64 + j] = Wo_w[j * NC + c] / colsum[c];
}

// ---------- out = expb @ Ws + b, LDS-tiled ----------
// j0 MUST be readfirstlane'd: makes Ws reads provably wave-uniform -> s_load.
__global__ void __launch_bounds__(256) k_out(const uint2* __restrict__ expb,
                                             const float* __restrict__ Ws,
                                             const float* __restrict__ Wo_b,
                                             float* __restrict__ out) {
    __shared__ unsigned tile[64][129];
    int n0 = blockIdx.x * 64;
    int rows = min(64, N_NODES - n0);
    int tid = threadIdx.x;

#pragma unroll
    for (int it = 0; it < 16; ++it) {
        int idx = tid + it * 256;          // 64 rows x 64 uint2
        int row = idx >> 6;                // wave-uniform per iteration
        int c4 = idx & 63;                 // lane-contiguous -> 512B bursts
        if (row < rows) {
            uint2 v = expb[(size_t)(n0 + row) * 64 + c4];
            tile[row][c4 * 2] = v.x;
            tile[row][c4 * 2 + 1] = v.y;
        }
    }
    __syncthreads();

    int nl = tid & 63;
    int j0 = __builtin_amdgcn_readfirstlane((tid >> 6) * 16);   // scalarize!
    int nr = min(nl, rows - 1);
    float acc[16];
#pragma unroll
    for (int jj = 0; jj < 16; ++jj) acc[jj] = 0.f;

#pragma unroll 2
    for (int cp = 0; cp < 128; ++cp) {     // 2 cols per iteration
        unsigned u = tile[nr][cp];
        float a0 = __uint_as_float(u << 16);
        float a1 = __uint_as_float(u & 0xFFFF0000u);
        const float* w0 = Ws + (2 * cp) * 64 + j0;   // wave-uniform -> s_load
        const float* w1 = w0 + 64;
#pragma unroll
        for (int jj = 0; jj < 16; ++jj)
            acc[jj] += a0 * w0[jj] + a1 * w1[jj];
    }

    if (nl < rows) {
        float* op = &out[(size_t)(n0 + nl) * DH + j0];
#pragma unroll
        for (int q = 0; q < 4; ++q) {
            float4 o;
            o.x = acc[q * 4 + 0] + Wo_b[j0 + q * 4 + 0];
            o.y = acc[q * 4 + 1] + Wo_b[j0 + q * 4 + 1];
            o.z = acc[q * 4 + 2] + Wo_b[j0 + q * 4 + 2];
            o.w = acc[q * 4 + 3] + Wo_b[j0 + q * 4 + 3];
            *(float4*)(op + q * 4) = o;
        }
    }
}

extern "C" void kernel_launch(void* const* d_in, const int* in_sizes, int n_in,
                              void* d_out, int out_size, void* d_ws, size_t ws_size,
                              hipStream_t stream) {
    const int*   ei   = (const int*)d_in[0];     // int32 from harness
    const float* x    = (const float*)d_in[1];
    const float* Ww   = (const float*)d_in[2];
    const float* Wb   = (const float*)d_in[3];
    const float* aw   = (const float*)d_in[4];
    const float* ab   = (const float*)d_in[5];
    const float* Wo_w = (const float*)d_in[6];
    const float* Wo_b = (const float*)d_in[7];
    float* out = (float*)d_out;

    char* p = (char*)d_ws;
    auto alloc = [&](size_t bytes) -> char* {
        char* q = p;
        p += (bytes + 255) & ~(size_t)255;
        return q;
    };
    uint2*    Wxb       = (uint2*)alloc((size_t)N_NODES * NC * 2);   // bf16 Wx copy
    uint4*    expb      = (uint4*)alloc((size_t)N_NODES * NC * 2);   // bf16 exp(agg)
    float*    Wt        = (float*)alloc((size_t)DX * NC * 4);
    float*    sic       = (float*)alloc((size_t)N_NODES * 4 * 4);
    float*    sjc       = (float*)alloc((size_t)N_NODES * 4 * 4);
    int*      rowstart  = (int*)alloc((size_t)(N_NODES + 1) * 4);
    int*      csr_src   = (int*)alloc((size_t)(N_EDGES + N_NODES) * 4);
    unsigned* binned    = (unsigned*)alloc((size_t)N_EDGES * 4);
    float*    colsum    = (float*)alloc(NC * 4);
    float*    Ws        = (float*)alloc(NC * DH * 4);
    int*      bcnt_part = (int*)alloc((size_t)BIN_BLOCKS * SCAN_BLOCKS * 4);
    int*      bbase     = (int*)alloc((SCAN_BLOCKS + 1) * 4);
    int*      bcur      = (int*)alloc(SCAN_BLOCKS * 4);

    k_bhist<<<BIN_BLOCKS, 256, 0, stream>>>(ei, bcnt_part, Ww, Wt, colsum);
    k_gemm1<<<(N_NODES / 8 + 3) / 4, 256, 0, stream>>>(x, Wt, Wb, aw, ab, Wxb, sic, sjc);
    k_scanb<<<1, 256, 0, stream>>>(bcnt_part, bbase, bcur);
    k_bin<<<BIN_BLOCKS, 256, 0, stream>>>(ei, bcur, binned);
    k_scatter3<<<SCAN_BLOCKS, 256, 0, stream>>>(binned, bbase, rowstart, csr_src);
    k_aggregate<<<N_NODES / 8, 256, 0, stream>>>(rowstart, csr_src, sic, sjc,
                                                 (const uint4*)Wxb, expb);
    k_colsum<<<256, 256, 0, stream>>>((const unsigned*)expb, colsum);
    k_prepWs<<<(NC * DH) / 256, 256, 0, stream>>>(Wo_w, colsum, Ws);
    k_out<<<(N_NODES + 63) / 64, 256, 0, stream>>>((const uint2*)expb, Ws, Wo_b, out);
}

// Round 15
// 407.233 us; speedup vs baseline: 1.0092x; 1.0092x over previous
//
#include <hip/hip_runtime.h>
#include <cfloat>

#define N_NODES 50000
#define N_EDGES 1600000
#define DX      128
#define DH      64
#define KH      4
#define NC      256                   // KH*DH
#define NEG_SLOPE 0.01f
#define SCAN_BLOCKS 196               // bucket count (dst>>8)
#define BIN_BLOCKS 250
#define BIN_CHUNK  6400               // 250*6400 = 1.6M edges exactly
#define GEMM_BLOCKS 1563              // ceil(50000/8/4)

__device__ __forceinline__ unsigned pack_bf16(float a, float b) {
    unsigned ua = __float_as_uint(a), ub = __float_as_uint(b);
    ua = (ua + 0x7FFFu + ((ua >> 16) & 1u)) >> 16;          // RNE
    ub = (ub + 0x7FFFu + ((ub >> 16) & 1u)) & 0xFFFF0000u;
    return ua | ub;
}

// ---------- tiny setup: transpose Ww -> Wt, zero colsum (must precede fused gemm) ----------
__global__ void k_setup(const float* __restrict__ Ww, float* __restrict__ Wt,
                        float* __restrict__ colsum) {
    int i = blockIdx.x * 256 + threadIdx.x;   // 32768
    if (i < NC) colsum[i] = 0.f;
    int d = i >> 8, c = i & 255;
    Wt[d * NC + c] = Ww[c * DX + d];
}

// ---------- fused: gemm1 blocks [0,1563) + bucket-histogram blocks [1563,1813) ----------
__global__ void __launch_bounds__(256) k_fused(const float* __restrict__ x,
                                               const float* __restrict__ Wt,
                                               const float* __restrict__ Wb,
                                               const float* __restrict__ aw,
                                               const float* __restrict__ ab,
                                               uint2* __restrict__ Wxb,
                                               float* __restrict__ sic,
                                               float* __restrict__ sjc,
                                               const int* __restrict__ ei,
                                               int* __restrict__ bcnt_part) {
    __shared__ int bh[SCAN_BLOCKS];
    if (blockIdx.x >= GEMM_BLOCKS) {
        // ---- bucket histogram chunk ----
        int t = threadIdx.x;
        if (t < SCAN_BLOCKS) bh[t] = 0;
        __syncthreads();
        int e0 = (blockIdx.x - GEMM_BLOCKS) * BIN_CHUNK;
#pragma unroll 5
        for (int k = 0; k < BIN_CHUNK / 256; ++k) {
            int dst = ei[N_EDGES + e0 + t + k * 256];
            atomicAdd(&bh[dst >> 8], 1);
        }
        __syncthreads();
        if (t < SCAN_BLOCKS)
            bcnt_part[(blockIdx.x - GEMM_BLOCKS) * SCAN_BLOCKS + t] = bh[t];
        return;
    }
    // ---- gemm1 ----
    int wave = blockIdx.x * 4 + __builtin_amdgcn_readfirstlane(threadIdx.x >> 6);
    if (wave >= N_NODES / 8) return;           // 50000 % 8 == 0
    int lane = threadIdx.x & 63;
    int kh = lane >> 4, lq = lane & 15;
    int n0 = wave * 8;
    const float4* WtV = (const float4*)Wt;
    float acc[8][4];
#pragma unroll
    for (int r = 0; r < 8; ++r)
#pragma unroll
        for (int q = 0; q < 4; ++q) acc[r][q] = 0.f;

    for (int d = 0; d < DX; d += 4) {
        float xr[8][4];
#pragma unroll
        for (int r = 0; r < 8; ++r) {
            float4 v = *(const float4*)&x[(size_t)(n0 + r) * DX + d];
            xr[r][0] = v.x; xr[r][1] = v.y; xr[r][2] = v.z; xr[r][3] = v.w;
        }
#pragma unroll
        for (int q = 0; q < 4; ++q) {
            float4 wv = WtV[(size_t)(d + q) * 64 + lane];
#pragma unroll
            for (int r = 0; r < 8; ++r) {
                acc[r][0] += xr[r][q] * wv.x;
                acc[r][1] += xr[r][q] * wv.y;
                acc[r][2] += xr[r][q] * wv.z;
                acc[r][3] += xr[r][q] * wv.w;
            }
        }
    }
    float4 bias = ((const float4*)Wb)[lane];
    const float* awi = aw + kh * 2 * DH + lq * 4;
    const float* awj = awi + DH;
    float ai0 = awi[0], ai1 = awi[1], ai2 = awi[2], ai3 = awi[3];
    float aj0 = awj[0], aj1 = awj[1], aj2 = awj[2], aj3 = awj[3];
    float abk = ab[kh];
#pragma unroll
    for (int r = 0; r < 8; ++r) {
        float o0 = acc[r][0] + bias.x, o1 = acc[r][1] + bias.y;
        float o2 = acc[r][2] + bias.z, o3 = acc[r][3] + bias.w;
        uint2 pk; pk.x = pack_bf16(o0, o1); pk.y = pack_bf16(o2, o3);
        Wxb[(size_t)(n0 + r) * 64 + lane] = pk;
        float pi = o0 * ai0 + o1 * ai1 + o2 * ai2 + o3 * ai3;
        float pj = o0 * aj0 + o1 * aj1 + o2 * aj2 + o3 * aj3;
#pragma unroll
        for (int off = 8; off >= 1; off >>= 1) {
            pi += __shfl_xor(pi, off, 64);
            pj += __shfl_xor(pj, off, 64);
        }
        if (lq == 0) {
            sic[(n0 + r) * 4 + kh] = pi + abk;   // fold ab into dst-side score
            sjc[(n0 + r) * 4 + kh] = pj;
        }
    }
}

// ---------- scan: bucket totals -> bbase; bcnt_part -> per-(block,bucket) bases ----------
__global__ void __launch_bounds__(256) k_scanb(int* __restrict__ bcnt_part,
                                               int* __restrict__ bbase) {
    __shared__ int s[256];
    int t = threadIdx.x;
    int tot = 0;
    if (t < SCAN_BLOCKS) {
        for (int b = 0; b < BIN_BLOCKS; ++b) {
            int v = bcnt_part[b * SCAN_BLOCKS + t];
            bcnt_part[b * SCAN_BLOCKS + t] = tot;   // local (within-bucket) prefix
            tot += v;
        }
    }
    s[t] = tot;
    __syncthreads();
#pragma unroll
    for (int off = 1; off < 256; off <<= 1) {
        int u = (t >= off) ? s[t - off] : 0;
        __syncthreads();
        s[t] += u;
        __syncthreads();
    }
    if (t < SCAN_BLOCKS) {
        int base = s[t] - tot;                      // exclusive bucket base
        bbase[t] = base;
        for (int b = 0; b < BIN_BLOCKS; ++b)
            bcnt_part[b * SCAN_BLOCKS + t] += base; // -> global base per (block,bucket)
    }
    if (t == SCAN_BLOCKS - 1) bbase[SCAN_BLOCKS] = s[t];   // = N_EDGES
}

// ---------- binning, single pass: bases precomputed by k_scanb ----------
__global__ void __launch_bounds__(256) k_bin(const int* __restrict__ ei,
                                             const int* __restrict__ bcnt_part,
                                             unsigned* __restrict__ binned) {
    __shared__ int bb[SCAN_BLOCKS];   // global base for this block's bucket runs
    __shared__ int bh[SCAN_BLOCKS];   // local cursor
    int t = threadIdx.x;
    if (t < SCAN_BLOCKS) {
        bb[t] = bcnt_part[blockIdx.x * SCAN_BLOCKS + t];
        bh[t] = 0;
    }
    __syncthreads();
    int e0 = blockIdx.x * BIN_CHUNK;
#pragma unroll 5
    for (int k = 0; k < BIN_CHUNK / 256; ++k) {
        int e = e0 + t + k * 256;
        int src = ei[e];
        int dst = ei[N_EDGES + e];
        int b = dst >> 8;
        int lo = atomicAdd(&bh[b], 1);
        binned[bb[b] + lo] = (unsigned)src | ((unsigned)(dst & 255) << 16);   // src < 2^16
    }
}

// ---------- fused per-bucket: count dsts + scan + rowstart + self-loop + scatter ----------
__global__ void __launch_bounds__(256) k_scatter3(const unsigned* __restrict__ binned,
                                                  const int* __restrict__ bbase,
                                                  int* __restrict__ rowstart,
                                                  int* __restrict__ csr_src) {
    __shared__ int lcnt[256];
    __shared__ int lcur[256];
    __shared__ int s[256];
    int t = threadIdx.x, b = blockIdx.x;
    int e0 = bbase[b], e1 = bbase[b + 1];
    lcnt[t] = 0;
    __syncthreads();
    for (int i = e0 + t; i < e1; i += 256)
        atomicAdd(&lcnt[binned[i] >> 16], 1);
    __syncthreads();
    int v = lcnt[t];
    s[t] = v;
    __syncthreads();
#pragma unroll
    for (int off = 1; off < 256; off <<= 1) {
        int u = (t >= off) ? s[t - off] : 0;
        __syncthreads();
        s[t] += u;
        __syncthreads();
    }
    int d = b * 256 + t;
    int base_b = e0 + 256 * b;              // edges before bucket + self-loops before bucket
    if (d < N_NODES) {
        int rs = base_b + (s[t] - v) + t;   // + t self-loops within bucket
        rowstart[d] = rs;
        csr_src[rs] = d;                    // self-loop edge placed first
        lcur[t] = rs + 1;
    } else lcur[t] = 0;
    if (b == 0 && t == 0) rowstart[N_NODES] = N_EDGES + N_NODES;
    __syncthreads();
    for (int i = e0 + t; i < e1; i += 256) {
        unsigned u = binned[i];
        int pos = atomicAdd(&lcur[u >> 16], 1);
        csr_src[pos] = (int)(u & 0xFFFFu);
    }
}

// ---------- aggregation (at its ~3.5 TB/s gather roofline — do not touch) ----------
__global__ void __launch_bounds__(256) k_aggregate(const int* __restrict__ rowstart,
                                                   const int* __restrict__ csr_src,
                                                   const float* __restrict__ sic,
                                                   const float* __restrict__ sjc,
                                                   const uint4* __restrict__ Wxb,
                                                   uint4* __restrict__ expb) {
    int tid = threadIdx.x;
    int dst = blockIdx.x * 8 + (tid >> 5);   // grid = 6250, exact
    int lq = tid & 31;
    int kh = lq >> 3;
    int i0 = rowstart[dst], iend = rowstart[dst + 1];
    float sval = sic[dst * 4 + kh];

    float den = 0.f;
    float a0 = 0.f, a1 = 0.f, a2 = 0.f, a3 = 0.f;
    float a4 = 0.f, a5 = 0.f, a6 = 0.f, a7 = 0.f;
    int i = i0;
    for (; i + 8 <= iend; i += 8) {
        int ss[8]; uint4 gg[8]; float tt[8];
#pragma unroll
        for (int u = 0; u < 8; ++u) ss[u] = csr_src[i + u];
#pragma unroll
        for (int u = 0; u < 8; ++u) gg[u] = Wxb[(size_t)ss[u] * 32 + lq];
#pragma unroll
        for (int u = 0; u < 8; ++u) tt[u] = sjc[ss[u] * 4 + kh];
#pragma unroll
        for (int u = 0; u < 8; ++u) {
            float e = sval + tt[u];
            e = (e >= 0.f) ? e : NEG_SLOPE * e;
            float ex = __expf(e);
            den += ex;
            a0 += ex * __uint_as_float(gg[u].x << 16);
            a1 += ex * __uint_as_float(gg[u].x & 0xFFFF0000u);
            a2 += ex * __uint_as_float(gg[u].y << 16);
            a3 += ex * __uint_as_float(gg[u].y & 0xFFFF0000u);
            a4 += ex * __uint_as_float(gg[u].z << 16);
            a5 += ex * __uint_as_float(gg[u].z & 0xFFFF0000u);
            a6 += ex * __uint_as_float(gg[u].w << 16);
            a7 += ex * __uint_as_float(gg[u].w & 0xFFFF0000u);
        }
    }
    for (; i < iend; ++i) {
        int s = csr_src[i];
        uint4 g = Wxb[(size_t)s * 32 + lq];
        float e = sval + sjc[s * 4 + kh];
        e = (e >= 0.f) ? e : NEG_SLOPE * e;
        float ex = __expf(e);
        den += ex;
        a0 += ex * __uint_as_float(g.x << 16);
        a1 += ex * __uint_as_float(g.x & 0xFFFF0000u);
        a2 += ex * __uint_as_float(g.y << 16);
        a3 += ex * __uint_as_float(g.y & 0xFFFF0000u);
        a4 += ex * __uint_as_float(g.z << 16);
        a5 += ex * __uint_as_float(g.z & 0xFFFF0000u);
        a6 += ex * __uint_as_float(g.w << 16);
        a7 += ex * __uint_as_float(g.w & 0xFFFF0000u);
    }
    float r = 1.f / den;
    uint4 pk;
    pk.x = pack_bf16(__expf(a0 * r), __expf(a1 * r));
    pk.y = pack_bf16(__expf(a2 * r), __expf(a3 * r));
    pk.z = pack_bf16(__expf(a4 * r), __expf(a5 * r));
    pk.w = pack_bf16(__expf(a6 * r), __expf(a7 * r));
    expb[(size_t)dst * 32 + lq] = pk;        // bf16 exp(agg), cols 8lq..8lq+7
}

// ---------- column sums of exp(agg), bf16 input, 2 cols/thread ----------
__global__ void __launch_bounds__(256) k_colsum(const unsigned* __restrict__ expb,
                                                float* __restrict__ colsum) {
    int tid = threadIdx.x;
    int cp = tid & 127;            // uint index within row (cols 2cp, 2cp+1)
    int ro = tid >> 7;             // row parity
    int base = blockIdx.x * 196;
    int r1 = min(base + 196, N_NODES);
    float s0 = 0.f, s1 = 0.f;
    for (int r = base + ro; r < r1; r += 2) {
        unsigned u = expb[(size_t)r * 128 + cp];
        s0 += __uint_as_float(u << 16);
        s1 += __uint_as_float(u & 0xFFFF0000u);
    }
    atomicAdd(&colsum[2 * cp], s0);
    atomicAdd(&colsum[2 * cp + 1], s1);
}

// ---------- Ws[c][j] = Wo_w[j][c] / colsum[c] ----------
__global__ void k_prepWs(const float* __restrict__ Wo_w, const float* __restrict__ colsum,
                         float* __restrict__ Ws) {
    int i = blockIdx.x * 256 + threadIdx.x;   // 16384 total
    int c = i >> 6, j = i & 63;
    Ws[c * 64 + j] = Wo_w[j * NC + c] / colsum[c];
}

// ---------- out = expb @ Ws + b, LDS-tiled ----------
// j0 MUST be readfirstlane'd: makes Ws reads provably wave-uniform -> s_load.
__global__ void __launch_bounds__(256) k_out(const uint2* __restrict__ expb,
                                             const float* __restrict__ Ws,
                                             const float* __restrict__ Wo_b,
                                             float* __restrict__ out) {
    __shared__ unsigned tile[64][129];
    int n0 = blockIdx.x * 64;
    int rows = min(64, N_NODES - n0);
    int tid = threadIdx.x;

#pragma unroll
    for (int it = 0; it < 16; ++it) {
        int idx = tid + it * 256;          // 64 rows x 64 uint2
        int row = idx >> 6;                // wave-uniform per iteration
        int c4 = idx & 63;                 // lane-contiguous -> 512B bursts
        if (row < rows) {
            uint2 v = expb[(size_t)(n0 + row) * 64 + c4];
            tile[row][c4 * 2] = v.x;
            tile[row][c4 * 2 + 1] = v.y;
        }
    }
    __syncthreads();

    int nl = tid & 63;
    int j0 = __builtin_amdgcn_readfirstlane((tid >> 6) * 16);   // scalarize!
    int nr = min(nl, rows - 1);
    float acc[16];
#pragma unroll
    for (int jj = 0; jj < 16; ++jj) acc[jj] = 0.f;

#pragma unroll 2
    for (int cp = 0; cp < 128; ++cp) {     // 2 cols per iteration
        unsigned u = tile[nr][cp];
        float a0 = __uint_as_float(u << 16);
        float a1 = __uint_as_float(u & 0xFFFF0000u);
        const float* w0 = Ws + (2 * cp) * 64 + j0;   // wave-uniform -> s_load
        const float* w1 = w0 + 64;
#pragma unroll
        for (int jj = 0; jj < 16; ++jj)
            acc[jj] += a0 * w0[jj] + a1 * w1[jj];
    }

    if (nl < rows) {
        float* op = &out[(size_t)(n0 + nl) * DH + j0];
#pragma unroll
        for (int q = 0; q < 4; ++q) {
            float4 o;
            o.x = acc[q * 4 + 0] + Wo_b[j0 + q * 4 + 0];
            o.y = acc[q * 4 + 1] + Wo_b[j0 + q * 4 + 1];
            o.z = acc[q * 4 + 2] + Wo_b[j0 + q * 4 + 2];
            o.w = acc[q * 4 + 3] + Wo_b[j0 + q * 4 + 3];
            *(float4*)(op + q * 4) = o;
        }
    }
}

extern "C" void kernel_launch(void* const* d_in, const int* in_sizes, int n_in,
                              void* d_out, int out_size, void* d_ws, size_t ws_size,
                              hipStream_t stream) {
    const int*   ei   = (const int*)d_in[0];     // int32 from harness
    const float* x    = (const float*)d_in[1];
    const float* Ww   = (const float*)d_in[2];
    const float* Wb   = (const float*)d_in[3];
    const float* aw   = (const float*)d_in[4];
    const float* ab   = (const float*)d_in[5];
    const float* Wo_w = (const float*)d_in[6];
    const float* Wo_b = (const float*)d_in[7];
    float* out = (float*)d_out;

    char* p = (char*)d_ws;
    auto alloc = [&](size_t bytes) -> char* {
        char* q = p;
        p += (bytes + 255) & ~(size_t)255;
        return q;
    };
    uint2*    Wxb       = (uint2*)alloc((size_t)N_NODES * NC * 2);   // bf16 Wx copy
    uint4*    expb      = (uint4*)alloc((size_t)N_NODES * NC * 2);   // bf16 exp(agg)
    float*    Wt        = (float*)alloc((size_t)DX * NC * 4);
    float*    sic       = (float*)alloc((size_t)N_NODES * 4 * 4);
    float*    sjc       = (float*)alloc((size_t)N_NODES * 4 * 4);
    int*      rowstart  = (int*)alloc((size_t)(N_NODES + 1) * 4);
    int*      csr_src   = (int*)alloc((size_t)(N_EDGES + N_NODES) * 4);
    unsigned* binned    = (unsigned*)alloc((size_t)N_EDGES * 4);
    float*    colsum    = (float*)alloc(NC * 4);
    float*    Ws        = (float*)alloc(NC * DH * 4);
    int*      bcnt_part = (int*)alloc((size_t)BIN_BLOCKS * SCAN_BLOCKS * 4);
    int*      bbase     = (int*)alloc((SCAN_BLOCKS + 1) * 4);

    k_setup<<<128, 256, 0, stream>>>(Ww, Wt, colsum);
    k_fused<<<GEMM_BLOCKS + BIN_BLOCKS, 256, 0, stream>>>(x, Wt, Wb, aw, ab, Wxb,
                                                          sic, sjc, ei, bcnt_part);
    k_scanb<<<1, 256, 0, stream>>>(bcnt_part, bbase);
    k_bin<<<BIN_BLOCKS, 256, 0, stream>>>(ei, bcnt_part, binned);
    k_scatter3<<<SCAN_BLOCKS, 256, 0, stream>>>(binned, bbase, rowstart, csr_src);
    k_aggregate<<<N_NODES / 8, 256, 0, stream>>>(rowstart, csr_src, sic, sjc,
                                                 (const uint4*)Wxb, expb);
    k_colsum<<<256, 256, 0, stream>>>((const unsigned*)expb, colsum);
    k_prepWs<<<(NC * DH) / 256, 256, 0, stream>>>(Wo_w, colsum, Ws);
    k_out<<<(N_NODES + 63) / 64, 256, 0, stream>>>((const uint2*)expb, Ws, Wo_b, out);
}